// Round 15
// baseline (411.825 us; speedup 1.0000x reference)
//
#include <hip/hip_runtime.h>

typedef __attribute__((ext_vector_type(8))) _Float16 half8;
typedef __attribute__((ext_vector_type(4))) _Float16 half4;
typedef __attribute__((ext_vector_type(4))) float floatx4;

#define DEVI __device__ __forceinline__

// =====================================================================
// R15: R14 (best, 404.8us) + 2x2 super-tiles on S-gemm and out-proj
// (R14 proved the mechanism on PV: 4x4 hot set competed with the C-write
// stream for L2; 2x2 frees capacity -> -11us). S-gemm streams a 64MB
// C-write while staging; out-proj streams 32MB y reads + 64MB fp32
// writes. Same lever, same arithmetic, applied to the remaining two.
// qkv keeps 4x4 (its B is 6MB L2-resident; C-write only 96MB across
// 3 rounds — and qkv is at its measured structure plateau 106us/46%).
// DEAD ENDS recorded: flash S+PV fusion infeasible at d=1024 (Q-in-reg
// ~256 VGPR, y-acc +128 VGPR, dv-split => 4x S recompute); B-direct
// refuted R13 (row-gather = 16 lines/VMEM instr); fp8 out of error
// budget (absmax already at 2^-9 granularity).
// Guards: VGPR 60, conflicts 0, absmax 0.00195, qkv ~106us.
// Everything else = R14: 128^2 staged GEMMs, launch_bounds(256,4),
// chunk-XOR LDS swizzle, XCD patch + super-tile order, fused exp(s-4)
// softmax + fp32 rowsum atomics, merged prep, 5 dispatches.
// =====================================================================

DEVI void gload_lds16(const _Float16* g, _Float16* l) {
    __builtin_amdgcn_global_load_lds(
        (const __attribute__((address_space(1))) void*)g,
        (__attribute__((address_space(3))) void*)l, 16, 0, 0);
}

// Stage a 128x64 fp16 tile (16 KB), chunk-XOR swizzled at 8-half
// granularity: LDS(r,p) holds global chunk p^(r&7); conflict-free
// readback (0 bank conflicts measured R0/R3-R14).
template <int LDG>
DEVI void stage128(const _Float16* __restrict__ g, _Float16* lds, int tid) {
#pragma unroll
    for (int it = 0; it < 4; ++it) {
        int s = it * 256 + tid;       // 1024 slots of 8 halfs
        int r = s >> 3, p = s & 7;
        int c = p ^ (r & 7);
        gload_lds16(g + (size_t)r * LDG + c * 8, lds + (size_t)s * 8);
    }
}

DEVI half8 frag(const _Float16* lds, int r, int ko) {
    return *(const half8*)&lds[r * 64 + (((ko >> 3) ^ (r & 7)) << 3)];
}

// A frag: A[m][k], m=lane&15, k=(lane>>4)*8+j ; B frag: B[k][n], n=lane&15
// C/D: col=lane&15, row=(lane>>4)*4+reg   (verified layouts, guide §3)
DEVI void mfma1_128(const _Float16* LA, const _Float16* LB,
                    floatx4 acc[4][4], int wm, int wn, int lane) {
    const int lr = lane & 15, quad = lane >> 4;
#pragma unroll
    for (int kk = 0; kk < 64; kk += 32) {
        const int ko = kk + quad * 8;
        half8 a[4], b[4];
#pragma unroll
        for (int i = 0; i < 4; ++i) {
            a[i] = frag(LA, wm * 64 + i * 16 + lr, ko);
            b[i] = frag(LB, wn * 64 + i * 16 + lr, ko);
        }
#pragma unroll
        for (int mi = 0; mi < 4; ++mi)
#pragma unroll
            for (int ni = 0; ni < 4; ++ni)
                acc[mi][ni] = __builtin_amdgcn_mfma_f32_16x16x32_f16(a[mi], b[ni], acc[mi][ni], 0, 0, 0);
    }
}

// SUPxSUP super-tile remap within an XCD's PXM x PXN tile region.
// j in [0, PXM*PXN); requires PXM%SUP==0 and (PXM*PXN)%(SUP*SUP)==0.
template <int SUP>
DEVI void remap2d(int j, int pxm_divS, int& bm, int& bn) {
    constexpr int S2 = SUP * SUP;
    const int jl = j % S2, js = j / S2;
    const int ms = js % pxm_divS, ns = js / pxm_divS;
    bm = ms * SUP + (jl % SUP);
    bn = ns * SUP + (jl / SUP);
}

// ---------------- merged prep: cast x, transpose+cast w, cast ow, zero rowsum
__global__ __launch_bounds__(256) void k_prep(
    const float* __restrict__ x, const float* __restrict__ w, const float* __restrict__ ow,
    _Float16* __restrict__ xh, _Float16* __restrict__ wh, _Float16* __restrict__ owh,
    float* __restrict__ rowsum)
{
    __shared__ float tile[32][33];
    const int bid = blockIdx.x, t = threadIdx.x;
    if (bid < 8192) {                       // x fp32 -> fp16, 8/thread
        size_t i = ((size_t)bid * 256 + t) * 8;
        float4 v0 = *(const float4*)(x + i);
        float4 v1 = *(const float4*)(x + i + 4);
        float vv[8] = {v0.x, v0.y, v0.z, v0.w, v1.x, v1.y, v1.z, v1.w};
        half8 h;
#pragma unroll
        for (int j = 0; j < 8; ++j) h[j] = (_Float16)vv[j];
        *(half8*)(xh + i) = h;
    } else if (bid < 11264) {               // w [1024][3072] -> wh [3072][1024]
        const int bx = bid - 8192;
        const int n0 = (bx % 96) * 32, k0 = (bx / 96) * 32;
#pragma unroll
        for (int it = 0; it < 4; ++it) {
            int idx = it * 256 + t;
            int kk = idx >> 5, nn = idx & 31;
            tile[kk][nn] = w[(size_t)(k0 + kk) * 3072 + n0 + nn];
        }
        __syncthreads();
#pragma unroll
        for (int it = 0; it < 4; ++it) {
            int idx = it * 256 + t;
            int nn = idx >> 5, kk = idx & 31;
            wh[(size_t)(n0 + nn) * 1024 + k0 + kk] = (_Float16)tile[kk][nn];
        }
    } else if (bid < 11776) {               // ow fp32 -> fp16
        size_t i = ((size_t)(bid - 11264) * 256 + t) * 8;
        float4 v0 = *(const float4*)(ow + i);
        float4 v1 = *(const float4*)(ow + i + 4);
        float vv[8] = {v0.x, v0.y, v0.z, v0.w, v1.x, v1.y, v1.z, v1.w};
        half8 h;
#pragma unroll
        for (int j = 0; j < 8; ++j) h[j] = (_Float16)vv[j];
        *(half8*)(owh + i) = h;
    } else {                                // zero rowsum [8][2048]
        rowsum[(bid - 11776) * 256 + t] = 0.f;
    }
}

// ---------------- qkv GEMM, 128x128 tile ----------------
__global__ __launch_bounds__(256, 4) void k_qkv(
    const _Float16* __restrict__ xh, const _Float16* __restrict__ wh,
    _Float16* __restrict__ qh, _Float16* __restrict__ kh, _Float16* __restrict__ vT)
{
    __shared__ __align__(16) _Float16 LA[128 * 64], LB[128 * 64];
    // XCD patch (16 M-tiles) + 4x4 super-tile order within the patch:
    // hot set = 4 A panels (1MB) + 4 B panels (1MB) << 4MB L2.
    const int lin = blockIdx.x;             // grid 3072 = 8 XCD x (16M x 24N)
    const int xcd = lin & 7, j = lin >> 3;  // j in [0,384)
    int bm, bn; remap2d<4>(j, 4, bm, bn);   // bm in [0,16), bn in [0,24)
    const int m0 = (xcd * 16 + bm) * 128, n0 = bn * 128;
    const int tid = threadIdx.x, lane = tid & 63, w = tid >> 6, wm = w >> 1, wn = w & 1;
    floatx4 acc[4][4];
    const floatx4 zf = {0.f, 0.f, 0.f, 0.f};
#pragma unroll
    for (int mi = 0; mi < 4; ++mi)
        for (int ni = 0; ni < 4; ++ni) acc[mi][ni] = zf;

    const _Float16* A = xh + (size_t)m0 * 1024;
    const _Float16* B = wh + (size_t)n0 * 1024;
    for (int kt = 0; kt < 16; ++kt) {
        stage128<1024>(A + kt * 64, LA, tid);
        stage128<1024>(B + kt * 64, LB, tid);
        __syncthreads();
        mfma1_128(LA, LB, acc, wm, wn, lane);
        __syncthreads();
    }

    const int lr = lane & 15, quad = lane >> 4;
    if (n0 < 1024) {            // q, scaled by 1/sqrt(1024)
#pragma unroll
        for (int mi = 0; mi < 4; ++mi)
            for (int ni = 0; ni < 4; ++ni)
                for (int r = 0; r < 4; ++r) {
                    int m = m0 + wm * 64 + mi * 16 + quad * 4 + r;
                    int n = n0 + wn * 64 + ni * 16 + lr;
                    qh[(size_t)m * 1024 + n] = (_Float16)(acc[mi][ni][r] * 0.03125f);
                }
    } else if (n0 < 2048) {     // k
#pragma unroll
        for (int mi = 0; mi < 4; ++mi)
            for (int ni = 0; ni < 4; ++ni)
                for (int r = 0; r < 4; ++r) {
                    int m = m0 + wm * 64 + mi * 16 + quad * 4 + r;
                    int n = n0 - 1024 + wn * 64 + ni * 16 + lr;
                    kh[(size_t)m * 1024 + n] = (_Float16)acc[mi][ni][r];
                }
    } else {                    // v, written transposed: vT[b][e][n-in-seq]
#pragma unroll
        for (int mi = 0; mi < 4; ++mi)
            for (int ni = 0; ni < 4; ++ni) {
                int mb = m0 + wm * 64 + mi * 16 + quad * 4;   // 4-aligned
                int b = mb >> 11, ml = mb & 2047;
                int e = n0 - 2048 + wn * 64 + ni * 16 + lr;
                half4 pk;
#pragma unroll
                for (int r = 0; r < 4; ++r) pk[r] = (_Float16)acc[mi][ni][r];
                *(half4*)&vT[((size_t)b * 1024 + e) * 2048 + ml] = pk;
            }
    }
}

// ---------------- generic 128x128 fp16 GEMM (fused epilogues) ------
// EPI 1: fp32 out + bias (out-proj)
// EPI 2: P = fp16(exp(acc-4)) + fp32 rowsum atomics  (S-gemm fused softmax)
// EPI 3: fp16(acc / rowsum[row])                     (PV)
// MODE 0: XCD = batch z; per-XCD region GX x GY tiles, SUPxSUP order.
// MODE 1: XCD owns GX/8 M-tiles x GY; SUPxSUP order.
template <int EPI, int K, int MODE, int GX, int GY, int SUP>
__global__ __launch_bounds__(256, 4) void k_gemm128(
    const _Float16* __restrict__ Ab, const _Float16* __restrict__ Bb,
    _Float16* __restrict__ C16, float* __restrict__ C32, const float* __restrict__ bias,
    float* __restrict__ rowsum,
    unsigned long long sAz, unsigned long long sBz, unsigned long long sCz, int ldc)
{
    __shared__ __align__(16) _Float16 LA[128 * 64], LB[128 * 64];
    const int lin = blockIdx.x;
    const int xcd = lin & 7, j = lin >> 3;
    int bx, by, bz, bm, bn;
    if (MODE == 0) {                    // per-XCD region: GX x GY
        remap2d<SUP>(j, GX / SUP, bm, bn);
        bz = xcd; bx = bm; by = bn;
    } else {                            // per-XCD region: (GX/8) x GY
        remap2d<SUP>(j, (GX / 8) / SUP, bm, bn);
        bz = 0; bx = xcd * (GX / 8) + bm; by = bn;
    }
    const int m0 = bx * 128, n0 = by * 128;
    const _Float16* A = Ab + (size_t)bz * sAz + (size_t)m0 * K;
    const _Float16* B = Bb + (size_t)bz * sBz + (size_t)n0 * K;
    const int tid = threadIdx.x, lane = tid & 63, w = tid >> 6, wm = w >> 1, wn = w & 1;
    floatx4 acc[4][4];
    const floatx4 zf = {0.f, 0.f, 0.f, 0.f};
#pragma unroll
    for (int mi = 0; mi < 4; ++mi)
        for (int ni = 0; ni < 4; ++ni) acc[mi][ni] = zf;
    for (int kt = 0; kt < (K >> 6); ++kt) {
        stage128<K>(A + kt * 64, LA, tid);
        stage128<K>(B + kt * 64, LB, tid);
        __syncthreads();
        mfma1_128(LA, LB, acc, wm, wn, lane);
        __syncthreads();
    }
    const int lr = lane & 15, quad = lane >> 4;

    if (EPI == 1) {             // out-proj: fp32 + bias
#pragma unroll
        for (int mi = 0; mi < 4; ++mi)
#pragma unroll
            for (int ni = 0; ni < 4; ++ni)
#pragma unroll
                for (int r = 0; r < 4; ++r) {
                    int m = m0 + wm * 64 + mi * 16 + quad * 4 + r;
                    int n = n0 + wn * 64 + ni * 16 + lr;
                    C32[(size_t)m * ldc + n] = acc[mi][ni][r] + bias[n];
                }
    } else if (EPI == 2) {      // fused softmax: P = exp(s-4), rowsum atomics
        float (*psum)[2] = (float(*)[2])LA;     // 128 rows x 2 wn, 1 KB
#pragma unroll
        for (int mi = 0; mi < 4; ++mi) {
            floatx4 rs = zf;
#pragma unroll
            for (int ni = 0; ni < 4; ++ni)
#pragma unroll
                for (int r = 0; r < 4; ++r) {
                    int m = m0 + wm * 64 + mi * 16 + quad * 4 + r;
                    int n = n0 + wn * 64 + ni * 16 + lr;
                    float p = __expf(acc[mi][ni][r] - 4.0f);
                    C16[(size_t)bz * sCz + (size_t)m * ldc + n] = (_Float16)p;
                    rs[r] += p;
                }
#pragma unroll
            for (int o = 1; o < 16; o <<= 1)
#pragma unroll
                for (int r = 0; r < 4; ++r) rs[r] += __shfl_xor(rs[r], o, 64);
            if (lr == 0) {
                int lrow = wm * 64 + mi * 16 + quad * 4;
#pragma unroll
                for (int r = 0; r < 4; ++r) psum[lrow + r][wn] = rs[r];
            }
        }
        __syncthreads();
        if (tid < 128)
            atomicAdd(&rowsum[(size_t)bz * 2048 + m0 + tid], psum[tid][0] + psum[tid][1]);
    } else {                    // EPI 3: PV, divide by row sum
#pragma unroll
        for (int mi = 0; mi < 4; ++mi) {
            const int mb = m0 + wm * 64 + mi * 16 + quad * 4;
            const float4 rsv = *(const float4*)&rowsum[(size_t)bz * 2048 + mb];
            const float* rsp = (const float*)&rsv;
#pragma unroll
            for (int ni = 0; ni < 4; ++ni)
#pragma unroll
                for (int r = 0; r < 4; ++r) {
                    int n = n0 + wn * 64 + ni * 16 + lr;
                    C16[(size_t)bz * sCz + (size_t)(mb + r) * ldc + n] =
                        (_Float16)(acc[mi][ni][r] / rsp[r]);
                }
        }
    }
}

// ---------------- launch ----------------
extern "C" void kernel_launch(void* const* d_in, const int* in_sizes, int n_in,
                              void* d_out, int out_size, void* d_ws, size_t ws_size,
                              hipStream_t stream) {
    const float* x  = (const float*)d_in[0];   // [8,2048,1024]
    const float* wq = (const float*)d_in[1];   // [1024,3072]
    const float* ow = (const float*)d_in[2];   // [1024,1024]
    const float* ob = (const float*)d_in[3];   // [1024]
    float* out = (float*)d_out;                // [8,2048,1024] fp32

    // workspace layout (bytes)
    char* ws = (char*)d_ws;
    _Float16* xh  = (_Float16*)(ws + 0);           // 32 MB (dead after qkv)
    _Float16* wh  = (_Float16*)(ws + 33554432);    // 6 MB  (dead after qkv)
    _Float16* S   = (_Float16*)(ws + 0);           // 64 MB [8][2048][2048] over xh+wh (holds P)
    _Float16* qh  = (_Float16*)(ws + 67108864);    // 32 MB (scaled 1/32)
    _Float16* kh  = (_Float16*)(ws + 100663296);   // 32 MB
    _Float16* vT  = (_Float16*)(ws + 134217728);   // 32 MB [8][1024][2048]
    _Float16* owh = (_Float16*)(ws + 167772160);   // 2 MB
    float*    rsF = (float*)(ws + 169869312);      // 64 KB [8][2048] fp32 row sums
    _Float16* y   = qh;                            // qh dead after S-gemm

    if (ws_size < 180355072ull) return;  // clean fail instead of OOB corruption

    // prep: cast x (8192) | prep w (3072) | prep ow (512) | zero rowsum (64)
    hipLaunchKernelGGL(k_prep, dim3(11840), dim3(256), 0, stream,
                       x, wq, ow, xh, wh, owh, rsF);
    hipLaunchKernelGGL(k_qkv, dim3(3072), dim3(256), 0, stream, xh, wh, qh, kh, vT);
    // P = exp(q k^T - 4) + row sums (over dead xh/wh region); XCD = batch
    // 2x2 supers: S-gemm streams a 64MB C-write; free L2 for it (R14 mech.)
    hipLaunchKernelGGL((k_gemm128<2, 1024, 0, 16, 16, 2>), dim3(2048), dim3(256), 0, stream,
                       qh, kh, S, (float*)nullptr, (const float*)nullptr, rsF,
                       2048ull * 1024, 2048ull * 1024, 2048ull * 2048, 2048);
    // y = (P V) / rowsum (y over dead qh region); XCD = batch; 2x2 supers
    hipLaunchKernelGGL((k_gemm128<3, 2048, 0, 16, 8, 2>), dim3(1024), dim3(256), 0, stream,
                       S, vT, y, (float*)nullptr, (const float*)nullptr, rsF,
                       2048ull * 2048, 1024ull * 2048, 2048ull * 1024, 1024);
    // out = y ow^T + b; XCD = M-chunk; 2x2 supers (streams 64MB fp32 write)
    hipLaunchKernelGGL((k_gemm128<1, 1024, 1, 128, 8, 2>), dim3(1024), dim3(256), 0, stream,
                       y, owh, (_Float16*)nullptr, out, ob, (float*)nullptr,
                       0ull, 0ull, 0ull, 1024);
}

// Round 16
// 404.376 us; speedup vs baseline: 1.0184x; 1.0184x over previous
//
#include <hip/hip_runtime.h>

typedef __attribute__((ext_vector_type(8))) _Float16 half8;
typedef __attribute__((ext_vector_type(4))) _Float16 half4;
typedef __attribute__((ext_vector_type(4))) float floatx4;

#define DEVI __device__ __forceinline__

// =====================================================================
// R16: REVERT to R14 exactly (measured session best, 404.8us).
// R15 post-mortem: super-tile size trades CAPACITY vs PANEL REUSE.
// 2x2 halves per-panel reuse (2 blocks/panel vs 4 -> ~2x panel fetch).
// PV (512KB panels): 4x4 hot set = 4MB = full L2 -> capacity-bound ->
// 2x2 wins (R14, -11us). S-gemm/out (256KB panels): 4x4 hot set = 2MB,
// fits fine -> reuse-bound -> 2x2 loses (R15, +7us). Optimum: PV 2x2,
// everything else 4x4 = exactly R14.
// Config ledger (all measured): 128^2 staged GEMMs (best of 128^2 vs
// five 256^2 schedules), launch_bounds(256,4) (best of 3/4/5),
// chunk-XOR LDS swizzle (0 conflicts), XCD patch + super-tile order
// (FETCH 202->74MB), fused exp(s-4) softmax + fp32 rowsum atomics
// (-22us vs separate softmax), merged prep, 5 dispatches.
// Guards: VGPR 60, conflicts 0, absmax 0.00195, qkv ~106us, total ~405.
// =====================================================================

DEVI void gload_lds16(const _Float16* g, _Float16* l) {
    __builtin_amdgcn_global_load_lds(
        (const __attribute__((address_space(1))) void*)g,
        (__attribute__((address_space(3))) void*)l, 16, 0, 0);
}

// Stage a 128x64 fp16 tile (16 KB), chunk-XOR swizzled at 8-half
// granularity: LDS(r,p) holds global chunk p^(r&7); conflict-free
// readback (0 bank conflicts measured R0/R3-R15).
template <int LDG>
DEVI void stage128(const _Float16* __restrict__ g, _Float16* lds, int tid) {
#pragma unroll
    for (int it = 0; it < 4; ++it) {
        int s = it * 256 + tid;       // 1024 slots of 8 halfs
        int r = s >> 3, p = s & 7;
        int c = p ^ (r & 7);
        gload_lds16(g + (size_t)r * LDG + c * 8, lds + (size_t)s * 8);
    }
}

DEVI half8 frag(const _Float16* lds, int r, int ko) {
    return *(const half8*)&lds[r * 64 + (((ko >> 3) ^ (r & 7)) << 3)];
}

// A frag: A[m][k], m=lane&15, k=(lane>>4)*8+j ; B frag: B[k][n], n=lane&15
// C/D: col=lane&15, row=(lane>>4)*4+reg   (verified layouts, guide §3)
DEVI void mfma1_128(const _Float16* LA, const _Float16* LB,
                    floatx4 acc[4][4], int wm, int wn, int lane) {
    const int lr = lane & 15, quad = lane >> 4;
#pragma unroll
    for (int kk = 0; kk < 64; kk += 32) {
        const int ko = kk + quad * 8;
        half8 a[4], b[4];
#pragma unroll
        for (int i = 0; i < 4; ++i) {
            a[i] = frag(LA, wm * 64 + i * 16 + lr, ko);
            b[i] = frag(LB, wn * 64 + i * 16 + lr, ko);
        }
#pragma unroll
        for (int mi = 0; mi < 4; ++mi)
#pragma unroll
            for (int ni = 0; ni < 4; ++ni)
                acc[mi][ni] = __builtin_amdgcn_mfma_f32_16x16x32_f16(a[mi], b[ni], acc[mi][ni], 0, 0, 0);
    }
}

// SUPxSUP super-tile remap within an XCD's PXM x PXN tile region.
// j in [0, PXM*PXN); requires PXM%SUP==0 and (PXM*PXN)%(SUP*SUP)==0.
template <int SUP>
DEVI void remap2d(int j, int pxm_divS, int& bm, int& bn) {
    constexpr int S2 = SUP * SUP;
    const int jl = j % S2, js = j / S2;
    const int ms = js % pxm_divS, ns = js / pxm_divS;
    bm = ms * SUP + (jl % SUP);
    bn = ns * SUP + (jl / SUP);
}

// ---------------- merged prep: cast x, transpose+cast w, cast ow, zero rowsum
__global__ __launch_bounds__(256) void k_prep(
    const float* __restrict__ x, const float* __restrict__ w, const float* __restrict__ ow,
    _Float16* __restrict__ xh, _Float16* __restrict__ wh, _Float16* __restrict__ owh,
    float* __restrict__ rowsum)
{
    __shared__ float tile[32][33];
    const int bid = blockIdx.x, t = threadIdx.x;
    if (bid < 8192) {                       // x fp32 -> fp16, 8/thread
        size_t i = ((size_t)bid * 256 + t) * 8;
        float4 v0 = *(const float4*)(x + i);
        float4 v1 = *(const float4*)(x + i + 4);
        float vv[8] = {v0.x, v0.y, v0.z, v0.w, v1.x, v1.y, v1.z, v1.w};
        half8 h;
#pragma unroll
        for (int j = 0; j < 8; ++j) h[j] = (_Float16)vv[j];
        *(half8*)(xh + i) = h;
    } else if (bid < 11264) {               // w [1024][3072] -> wh [3072][1024]
        const int bx = bid - 8192;
        const int n0 = (bx % 96) * 32, k0 = (bx / 96) * 32;
#pragma unroll
        for (int it = 0; it < 4; ++it) {
            int idx = it * 256 + t;
            int kk = idx >> 5, nn = idx & 31;
            tile[kk][nn] = w[(size_t)(k0 + kk) * 3072 + n0 + nn];
        }
        __syncthreads();
#pragma unroll
        for (int it = 0; it < 4; ++it) {
            int idx = it * 256 + t;
            int nn = idx >> 5, kk = idx & 31;
            wh[(size_t)(n0 + nn) * 1024 + k0 + kk] = (_Float16)tile[kk][nn];
        }
    } else if (bid < 11776) {               // ow fp32 -> fp16
        size_t i = ((size_t)(bid - 11264) * 256 + t) * 8;
        float4 v0 = *(const float4*)(ow + i);
        float4 v1 = *(const float4*)(ow + i + 4);
        float vv[8] = {v0.x, v0.y, v0.z, v0.w, v1.x, v1.y, v1.z, v1.w};
        half8 h;
#pragma unroll
        for (int j = 0; j < 8; ++j) h[j] = (_Float16)vv[j];
        *(half8*)(owh + i) = h;
    } else {                                // zero rowsum [8][2048]
        rowsum[(bid - 11776) * 256 + t] = 0.f;
    }
}

// ---------------- qkv GEMM, 128x128 tile ----------------
__global__ __launch_bounds__(256, 4) void k_qkv(
    const _Float16* __restrict__ xh, const _Float16* __restrict__ wh,
    _Float16* __restrict__ qh, _Float16* __restrict__ kh, _Float16* __restrict__ vT)
{
    __shared__ __align__(16) _Float16 LA[128 * 64], LB[128 * 64];
    // XCD patch (16 M-tiles) + 4x4 super-tile order within the patch:
    // hot set = 4 A panels (1MB) + 4 B panels (1MB) << 4MB L2.
    const int lin = blockIdx.x;             // grid 3072 = 8 XCD x (16M x 24N)
    const int xcd = lin & 7, j = lin >> 3;  // j in [0,384)
    int bm, bn; remap2d<4>(j, 4, bm, bn);   // bm in [0,16), bn in [0,24)
    const int m0 = (xcd * 16 + bm) * 128, n0 = bn * 128;
    const int tid = threadIdx.x, lane = tid & 63, w = tid >> 6, wm = w >> 1, wn = w & 1;
    floatx4 acc[4][4];
    const floatx4 zf = {0.f, 0.f, 0.f, 0.f};
#pragma unroll
    for (int mi = 0; mi < 4; ++mi)
        for (int ni = 0; ni < 4; ++ni) acc[mi][ni] = zf;

    const _Float16* A = xh + (size_t)m0 * 1024;
    const _Float16* B = wh + (size_t)n0 * 1024;
    for (int kt = 0; kt < 16; ++kt) {
        stage128<1024>(A + kt * 64, LA, tid);
        stage128<1024>(B + kt * 64, LB, tid);
        __syncthreads();
        mfma1_128(LA, LB, acc, wm, wn, lane);
        __syncthreads();
    }

    const int lr = lane & 15, quad = lane >> 4;
    if (n0 < 1024) {            // q, scaled by 1/sqrt(1024)
#pragma unroll
        for (int mi = 0; mi < 4; ++mi)
            for (int ni = 0; ni < 4; ++ni)
                for (int r = 0; r < 4; ++r) {
                    int m = m0 + wm * 64 + mi * 16 + quad * 4 + r;
                    int n = n0 + wn * 64 + ni * 16 + lr;
                    qh[(size_t)m * 1024 + n] = (_Float16)(acc[mi][ni][r] * 0.03125f);
                }
    } else if (n0 < 2048) {     // k
#pragma unroll
        for (int mi = 0; mi < 4; ++mi)
            for (int ni = 0; ni < 4; ++ni)
                for (int r = 0; r < 4; ++r) {
                    int m = m0 + wm * 64 + mi * 16 + quad * 4 + r;
                    int n = n0 - 1024 + wn * 64 + ni * 16 + lr;
                    kh[(size_t)m * 1024 + n] = (_Float16)acc[mi][ni][r];
                }
    } else {                    // v, written transposed: vT[b][e][n-in-seq]
#pragma unroll
        for (int mi = 0; mi < 4; ++mi)
            for (int ni = 0; ni < 4; ++ni) {
                int mb = m0 + wm * 64 + mi * 16 + quad * 4;   // 4-aligned
                int b = mb >> 11, ml = mb & 2047;
                int e = n0 - 2048 + wn * 64 + ni * 16 + lr;
                half4 pk;
#pragma unroll
                for (int r = 0; r < 4; ++r) pk[r] = (_Float16)acc[mi][ni][r];
                *(half4*)&vT[((size_t)b * 1024 + e) * 2048 + ml] = pk;
            }
    }
}

// ---------------- generic 128x128 fp16 GEMM (fused epilogues) ------
// EPI 1: fp32 out + bias (out-proj)
// EPI 2: P = fp16(exp(acc-4)) + fp32 rowsum atomics  (S-gemm fused softmax)
// EPI 3: fp16(acc / rowsum[row])                     (PV)
// MODE 0: XCD = batch z; per-XCD region GX x GY tiles, SUPxSUP order.
// MODE 1: XCD owns GX/8 M-tiles x GY; SUPxSUP order.
template <int EPI, int K, int MODE, int GX, int GY, int SUP>
__global__ __launch_bounds__(256, 4) void k_gemm128(
    const _Float16* __restrict__ Ab, const _Float16* __restrict__ Bb,
    _Float16* __restrict__ C16, float* __restrict__ C32, const float* __restrict__ bias,
    float* __restrict__ rowsum,
    unsigned long long sAz, unsigned long long sBz, unsigned long long sCz, int ldc)
{
    __shared__ __align__(16) _Float16 LA[128 * 64], LB[128 * 64];
    const int lin = blockIdx.x;
    const int xcd = lin & 7, j = lin >> 3;
    int bx, by, bz, bm, bn;
    if (MODE == 0) {                    // per-XCD region: GX x GY
        remap2d<SUP>(j, GX / SUP, bm, bn);
        bz = xcd; bx = bm; by = bn;
    } else {                            // per-XCD region: (GX/8) x GY
        remap2d<SUP>(j, (GX / 8) / SUP, bm, bn);
        bz = 0; bx = xcd * (GX / 8) + bm; by = bn;
    }
    const int m0 = bx * 128, n0 = by * 128;
    const _Float16* A = Ab + (size_t)bz * sAz + (size_t)m0 * K;
    const _Float16* B = Bb + (size_t)bz * sBz + (size_t)n0 * K;
    const int tid = threadIdx.x, lane = tid & 63, w = tid >> 6, wm = w >> 1, wn = w & 1;
    floatx4 acc[4][4];
    const floatx4 zf = {0.f, 0.f, 0.f, 0.f};
#pragma unroll
    for (int mi = 0; mi < 4; ++mi)
        for (int ni = 0; ni < 4; ++ni) acc[mi][ni] = zf;
    for (int kt = 0; kt < (K >> 6); ++kt) {
        stage128<K>(A + kt * 64, LA, tid);
        stage128<K>(B + kt * 64, LB, tid);
        __syncthreads();
        mfma1_128(LA, LB, acc, wm, wn, lane);
        __syncthreads();
    }
    const int lr = lane & 15, quad = lane >> 4;

    if (EPI == 1) {             // out-proj: fp32 + bias
#pragma unroll
        for (int mi = 0; mi < 4; ++mi)
#pragma unroll
            for (int ni = 0; ni < 4; ++ni)
#pragma unroll
                for (int r = 0; r < 4; ++r) {
                    int m = m0 + wm * 64 + mi * 16 + quad * 4 + r;
                    int n = n0 + wn * 64 + ni * 16 + lr;
                    C32[(size_t)m * ldc + n] = acc[mi][ni][r] + bias[n];
                }
    } else if (EPI == 2) {      // fused softmax: P = exp(s-4), rowsum atomics
        float (*psum)[2] = (float(*)[2])LA;     // 128 rows x 2 wn, 1 KB
#pragma unroll
        for (int mi = 0; mi < 4; ++mi) {
            floatx4 rs = zf;
#pragma unroll
            for (int ni = 0; ni < 4; ++ni)
#pragma unroll
                for (int r = 0; r < 4; ++r) {
                    int m = m0 + wm * 64 + mi * 16 + quad * 4 + r;
                    int n = n0 + wn * 64 + ni * 16 + lr;
                    float p = __expf(acc[mi][ni][r] - 4.0f);
                    C16[(size_t)bz * sCz + (size_t)m * ldc + n] = (_Float16)p;
                    rs[r] += p;
                }
#pragma unroll
            for (int o = 1; o < 16; o <<= 1)
#pragma unroll
                for (int r = 0; r < 4; ++r) rs[r] += __shfl_xor(rs[r], o, 64);
            if (lr == 0) {
                int lrow = wm * 64 + mi * 16 + quad * 4;
#pragma unroll
                for (int r = 0; r < 4; ++r) psum[lrow + r][wn] = rs[r];
            }
        }
        __syncthreads();
        if (tid < 128)
            atomicAdd(&rowsum[(size_t)bz * 2048 + m0 + tid], psum[tid][0] + psum[tid][1]);
    } else {                    // EPI 3: PV, divide by row sum
#pragma unroll
        for (int mi = 0; mi < 4; ++mi) {
            const int mb = m0 + wm * 64 + mi * 16 + quad * 4;
            const float4 rsv = *(const float4*)&rowsum[(size_t)bz * 2048 + mb];
            const float* rsp = (const float*)&rsv;
#pragma unroll
            for (int ni = 0; ni < 4; ++ni)
#pragma unroll
                for (int r = 0; r < 4; ++r) {
                    int n = n0 + wn * 64 + ni * 16 + lr;
                    C16[(size_t)bz * sCz + (size_t)(mb + r) * ldc + n] =
                        (_Float16)(acc[mi][ni][r] / rsp[r]);
                }
        }
    }
}

// ---------------- launch ----------------
extern "C" void kernel_launch(void* const* d_in, const int* in_sizes, int n_in,
                              void* d_out, int out_size, void* d_ws, size_t ws_size,
                              hipStream_t stream) {
    const float* x  = (const float*)d_in[0];   // [8,2048,1024]
    const float* wq = (const float*)d_in[1];   // [1024,3072]
    const float* ow = (const float*)d_in[2];   // [1024,1024]
    const float* ob = (const float*)d_in[3];   // [1024]
    float* out = (float*)d_out;                // [8,2048,1024] fp32

    // workspace layout (bytes)
    char* ws = (char*)d_ws;
    _Float16* xh  = (_Float16*)(ws + 0);           // 32 MB (dead after qkv)
    _Float16* wh  = (_Float16*)(ws + 33554432);    // 6 MB  (dead after qkv)
    _Float16* S   = (_Float16*)(ws + 0);           // 64 MB [8][2048][2048] over xh+wh (holds P)
    _Float16* qh  = (_Float16*)(ws + 67108864);    // 32 MB (scaled 1/32)
    _Float16* kh  = (_Float16*)(ws + 100663296);   // 32 MB
    _Float16* vT  = (_Float16*)(ws + 134217728);   // 32 MB [8][1024][2048]
    _Float16* owh = (_Float16*)(ws + 167772160);   // 2 MB
    float*    rsF = (float*)(ws + 169869312);      // 64 KB [8][2048] fp32 row sums
    _Float16* y   = qh;                            // qh dead after S-gemm

    if (ws_size < 180355072ull) return;  // clean fail instead of OOB corruption

    // prep: cast x (8192) | prep w (3072) | prep ow (512) | zero rowsum (64)
    hipLaunchKernelGGL(k_prep, dim3(11840), dim3(256), 0, stream,
                       x, wq, ow, xh, wh, owh, rsF);
    hipLaunchKernelGGL(k_qkv, dim3(3072), dim3(256), 0, stream, xh, wh, qh, kh, vT);
    // P = exp(q k^T - 4) + row sums (over dead xh/wh region); XCD = batch; 4x4
    hipLaunchKernelGGL((k_gemm128<2, 1024, 0, 16, 16, 4>), dim3(2048), dim3(256), 0, stream,
                       qh, kh, S, (float*)nullptr, (const float*)nullptr, rsF,
                       2048ull * 1024, 2048ull * 1024, 2048ull * 2048, 2048);
    // y = (P V) / rowsum (y over dead qh region); XCD = batch; 2x2 supers
    // (K=2048 panels are 512KB: 4x4 hot set = 4MB = full L2; 2x2 = 2MB)
    hipLaunchKernelGGL((k_gemm128<3, 2048, 0, 16, 8, 2>), dim3(1024), dim3(256), 0, stream,
                       S, vT, y, (float*)nullptr, (const float*)nullptr, rsF,
                       2048ull * 2048, 1024ull * 2048, 2048ull * 1024, 1024);
    // out = y ow^T + b; XCD = M-chunk; 4x4
    hipLaunchKernelGGL((k_gemm128<1, 1024, 1, 128, 8, 4>), dim3(1024), dim3(256), 0, stream,
                       y, owh, (_Float16*)nullptr, out, ob, (float*)nullptr,
                       0ull, 0ull, 0ull, 1024);
}